// Round 1
// baseline (230.109 us; speedup 1.0000x reference)
//
#include <hip/hip_runtime.h>

#define BATCH 4
#define NDIM 2048
#define MDIM 2048
#define CDIM 128

// One block computes a 64x64 output tile for one batch.
// LDS: full-K (128) tiles of A (src rows) and B (tgt rows), XOR-swizzled in
// float4 chunks so tile = exactly 64 KiB total -> 2 blocks/CU (160 KiB pool).
// Row squared-norms are computed during the load phase with 32-lane shuffle
// reductions (the 32 float4 chunks of each row land on 32 consecutive lanes),
// then stashed into the (dead after compute) first LDS row for the epilogue.
__global__ __launch_bounds__(256) void sim_kernel(
    const float* __restrict__ src,
    const float* __restrict__ tgt,
    float* __restrict__ out)
{
    __shared__ float As[64 * 128];
    __shared__ float Bs[64 * 128];

    const int tid = threadIdx.x;
    const int b   = blockIdx.z;
    const int n0  = blockIdx.y << 6;
    const int m0  = blockIdx.x << 6;

    const float4* srcb = (const float4*)(src + ((size_t)b * NDIM + n0) * CDIM);
    const float4* tgtb = (const float4*)(tgt + ((size_t)b * MDIM + m0) * CDIM);

    float rowsa[8], rowsb[8];

    // Load 64x128 tiles: 2048 float4 per tile, 8 per thread. idx = row*32+c4,
    // consecutive lanes -> consecutive float4 -> perfectly coalesced.
    #pragma unroll
    for (int it = 0; it < 8; ++it) {
        int idx = tid + it * 256;
        int row = idx >> 5;
        int c4  = idx & 31;
        float4 va = srcb[idx];
        float4 vb = tgtb[idx];
        int pc = c4 ^ (row & 7);                 // XOR swizzle breaks bank conflicts
        *(float4*)&As[row * 128 + pc * 4] = va;
        *(float4*)&Bs[row * 128 + pc * 4] = vb;
        float sa = va.x * va.x + va.y * va.y + va.z * va.z + va.w * va.w;
        float sb = vb.x * vb.x + vb.y * vb.y + vb.z * vb.z + vb.w * vb.w;
        #pragma unroll
        for (int off = 16; off >= 1; off >>= 1) {   // reduce 32 lanes -> lane 0 of group
            sa += __shfl_down(sa, off, 32);
            sb += __shfl_down(sb, off, 32);
        }
        rowsa[it] = sa;   // valid in lanes with (tid&31)==0
        rowsb[it] = sb;
    }
    __syncthreads();

    // Cyclic 4x4 micro-tile: rows ty+16i, cols tx+16j.
    const int tx = tid & 15;
    const int ty = tid >> 4;

    float acc[4][4];
    #pragma unroll
    for (int i = 0; i < 4; ++i)
        #pragma unroll
        for (int j = 0; j < 4; ++j) acc[i][j] = 0.0f;

    #pragma unroll 4
    for (int k4 = 0; k4 < 32; ++k4) {
        float4 a[4], bv[4];
        #pragma unroll
        for (int i = 0; i < 4; ++i) {
            int ra = ty + 16 * i;
            a[i] = *(const float4*)&As[ra * 128 + ((k4 ^ (ra & 7)) << 2)];
        }
        #pragma unroll
        for (int j = 0; j < 4; ++j) {
            int rb = tx + 16 * j;
            bv[j] = *(const float4*)&Bs[rb * 128 + ((k4 ^ (rb & 7)) << 2)];
        }
        #pragma unroll
        for (int i = 0; i < 4; ++i)
            #pragma unroll
            for (int j = 0; j < 4; ++j)
                acc[i][j] += a[i].x * bv[j].x + a[i].y * bv[j].y
                           + a[i].z * bv[j].z + a[i].w * bv[j].w;
    }

    __syncthreads();   // all tile reads complete -> safe to overwrite As row 0
    if ((tid & 31) == 0) {
        int rbase = tid >> 5;
        #pragma unroll
        for (int it = 0; it < 8; ++it) {
            int row = rbase + it * 8;
            As[row]      = rowsa[it];   // ssq for tile row
            As[64 + row] = rowsb[it];   // tsq for tile row
        }
    }
    __syncthreads();

    float sqn[4], invn[4], sqm[4], invm[4];
    #pragma unroll
    for (int i = 0; i < 4; ++i) {
        float q = As[ty + 16 * i];
        sqn[i]  = q;
        invn[i] = 1.0f / fmaxf(sqrtf(q), 1e-12f);
        float p = As[64 + tx + 16 * i];
        sqm[i]  = p;
        invm[i] = 1.0f / fmaxf(sqrtf(p), 1e-12f);
    }

    float2* out2 = (float2*)out;
    #pragma unroll
    for (int i = 0; i < 4; ++i) {
        size_t rowbase = ((size_t)b * NDIM + (size_t)(n0 + ty + 16 * i)) * MDIM + m0;
        #pragma unroll
        for (int j = 0; j < 4; ++j) {
            float d   = acc[i][j];
            float cs  = d * invn[i] * invm[j];
            float dsq = sqn[i] + sqm[j] - 2.0f * d;
            float fd  = sqrtf(fmaxf(dsq, 0.0f));
            float fdn = 1.0f / (1.0f + fd);
            out2[rowbase + tx + 16 * j] = make_float2(cs, fdn);
        }
    }
}

extern "C" void kernel_launch(void* const* d_in, const int* in_sizes, int n_in,
                              void* d_out, int out_size, void* d_ws, size_t ws_size,
                              hipStream_t stream) {
    const float* src = (const float*)d_in[0];
    const float* tgt = (const float*)d_in[1];
    float* out = (float*)d_out;
    dim3 grid(MDIM / 64, NDIM / 64, BATCH);
    sim_kernel<<<grid, dim3(256), 0, stream>>>(src, tgt, out);
}

// Round 2
// 147.552 us; speedup vs baseline: 1.5595x; 1.5595x over previous
//
#include <hip/hip_runtime.h>

#define BATCH 4
#define NDIM 2048
#define MDIM 2048
#define CDIM 128

typedef short bf16x8 __attribute__((ext_vector_type(8)));   // 8 bf16 (4 VGPRs)
typedef float f32x4  __attribute__((ext_vector_type(4)));   // MFMA accumulator

// fp32 -> bf16 bits, round-to-nearest-even (inputs are finite normals).
__device__ __forceinline__ unsigned short f2bf(float f) {
    union { float f; unsigned int u; } v; v.f = f;
    unsigned int u = v.u;
    return (unsigned short)((u + 0x7FFFu + ((u >> 16) & 1u)) >> 16);
}

// Kernel 1: per-row squared norms in fp32.
// ws[0..8191]      = ssq for src rows (b*2048+n)
// ws[8192..16383]  = tsq for tgt rows
__global__ __launch_bounds__(256) void norm_kernel(
    const float* __restrict__ src, const float* __restrict__ tgt,
    float* __restrict__ ws)
{
    int gid  = blockIdx.x * 256 + threadIdx.x;
    int wid  = gid >> 6;          // one wave per row, 16384 waves
    int lane = gid & 63;
    const float* base = (wid < BATCH * NDIM)
        ? (src + (size_t)wid * CDIM)
        : (tgt + (size_t)(wid - BATCH * NDIM) * CDIM);
    float2 v = ((const float2*)base)[lane];
    float s = v.x * v.x + v.y * v.y;
    #pragma unroll
    for (int off = 32; off >= 1; off >>= 1) s += __shfl_xor(s, off, 64);
    if (lane == 0) ws[wid] = s;
}

// Kernel 2: 128x128 output tile per block; bf16 MFMA dots, fused epilogue.
// LDS = exactly 64 KiB: 2 x (128 rows x 128 bf16), XOR-swizzled in 16B chunks
// (chunk ^ (row & 15)) so MFMA fragment reads are <=2-way (free) and the
// staging writes are structural-minimum.
__global__ __launch_bounds__(256) void sim_mfma(
    const float* __restrict__ src, const float* __restrict__ tgt,
    const float* __restrict__ ws, float* __restrict__ out)
{
    __shared__ unsigned short As[128 * 128];   // src tile, bf16 bits
    __shared__ unsigned short Bs[128 * 128];   // tgt tile, bf16 bits

    const int tid = threadIdx.x;
    const int b   = blockIdx.z;
    const int i0  = blockIdx.y << 7;   // src-row base of tile
    const int j0  = blockIdx.x << 7;   // tgt-row base of tile

    const float4* s4 = (const float4*)(src + ((size_t)b * NDIM + i0) * CDIM);
    const float4* t4 = (const float4*)(tgt + ((size_t)b * MDIM + j0) * CDIM);

    // Stage 128x128 fp32 -> bf16 into LDS. 4096 float4 per tensor, 16/thread.
    #pragma unroll 4
    for (int it = 0; it < 16; ++it) {
        int idx  = tid + it * 256;
        int row  = idx >> 5;           // 0..127
        int c4   = idx & 31;           // float4 chunk within row
        float4 va = s4[idx];
        float4 vb = t4[idx];
        int chunk = c4 >> 1;           // 16B chunk (8 bf16)
        int half  = c4 & 1;
        int off   = row * 128 + (((chunk ^ (row & 15)) << 3) + (half << 2));
        ushort4 ua, ub;
        ua.x = f2bf(va.x); ua.y = f2bf(va.y); ua.z = f2bf(va.z); ua.w = f2bf(va.w);
        ub.x = f2bf(vb.x); ub.y = f2bf(vb.y); ub.z = f2bf(vb.z); ub.w = f2bf(vb.w);
        *(ushort4*)&As[off] = ua;
        *(ushort4*)&Bs[off] = ub;
    }
    __syncthreads();

    const int wave = tid >> 6;
    const int lane = tid & 63;
    const int wm   = (wave & 1) << 6;   // 64x64 quadrant per wave
    const int wn   = (wave >> 1) << 6;
    const int l16  = lane & 15;
    const int q    = lane >> 4;

    f32x4 acc[4][4];
    #pragma unroll
    for (int i = 0; i < 4; ++i)
        #pragma unroll
        for (int j = 0; j < 4; ++j) acc[i][j] = (f32x4){0.f, 0.f, 0.f, 0.f};

    // K = 128 in 4 MFMA steps of 32. A/B frag: lane holds row (wX+i*16+l16),
    // k = k0 + q*8 .. +7. Row%16 == l16, so swizzle = chunk ^ l16.
    #pragma unroll
    for (int k0 = 0; k0 < 4; ++k0) {
        int chunk = (k0 << 2) + q;     // (k0*32 + q*8) / 8
        int swz   = (chunk ^ l16) << 3;
        bf16x8 a[4], bv[4];
        #pragma unroll
        for (int i = 0; i < 4; ++i)
            a[i] = *(const bf16x8*)&As[(wm + (i << 4) + l16) * 128 + swz];
        #pragma unroll
        for (int j = 0; j < 4; ++j)
            bv[j] = *(const bf16x8*)&Bs[(wn + (j << 4) + l16) * 128 + swz];
        #pragma unroll
        for (int i = 0; i < 4; ++i)
            #pragma unroll
            for (int j = 0; j < 4; ++j)
                acc[i][j] = __builtin_amdgcn_mfma_f32_16x16x32_bf16(
                    a[i], bv[j], acc[i][j], 0, 0, 0);
    }

    // Epilogue. D layout: col(n) = lane&15, row(m) = q*4 + reg.
    const float* nrmS = ws + (size_t)b * NDIM + i0;
    const float* nrmT = ws + (size_t)BATCH * NDIM + (size_t)b * MDIM + j0;

    float sq[4][4], isq[4][4];
    #pragma unroll
    for (int i = 0; i < 4; ++i) {
        float4 s4v = *(const float4*)&nrmS[wm + (i << 4) + (q << 2)];
        sq[i][0] = s4v.x; sq[i][1] = s4v.y; sq[i][2] = s4v.z; sq[i][3] = s4v.w;
        #pragma unroll
        for (int r = 0; r < 4; ++r)
            isq[i][r] = __builtin_amdgcn_rsqf(fmaxf(sq[i][r], 1e-24f));
    }
    float tq[4], itq[4];
    #pragma unroll
    for (int j = 0; j < 4; ++j) {
        tq[j]  = nrmT[wn + (j << 4) + l16];
        itq[j] = __builtin_amdgcn_rsqf(fmaxf(tq[j], 1e-24f));
    }

    float2* out2 = (float2*)out;
    #pragma unroll
    for (int i = 0; i < 4; ++i) {
        #pragma unroll
        for (int r = 0; r < 4; ++r) {
            int mrow = wm + (i << 4) + (q << 2) + r;          // src idx in tile
            size_t rowbase = ((size_t)b * NDIM + (size_t)(i0 + mrow)) * MDIM + j0;
            float sqr = sq[i][r], isr = isq[i][r];
            #pragma unroll
            for (int j = 0; j < 4; ++j) {
                int ncol = wn + (j << 4) + l16;               // tgt idx in tile
                float d   = acc[i][j][r];
                float cs  = d * isr * itq[j];
                float dsq = sqr + tq[j] - 2.0f * d;
                float fd  = __builtin_amdgcn_sqrtf(fmaxf(dsq, 0.0f));
                float fdn = __builtin_amdgcn_rcpf(1.0f + fd);
                out2[rowbase + ncol] = make_float2(cs, fdn);
            }
        }
    }
}

extern "C" void kernel_launch(void* const* d_in, const int* in_sizes, int n_in,
                              void* d_out, int out_size, void* d_ws, size_t ws_size,
                              hipStream_t stream) {
    const float* src = (const float*)d_in[0];
    const float* tgt = (const float*)d_in[1];
    float* ws  = (float*)d_ws;
    float* out = (float*)d_out;

    // 16384 rows, one wave each -> 4096 blocks of 256.
    norm_kernel<<<dim3(4096), dim3(256), 0, stream>>>(src, tgt, ws);

    dim3 grid(MDIM / 128, NDIM / 128, BATCH);
    sim_mfma<<<grid, dim3(256), 0, stream>>>(src, tgt, ws, out);
}